// Round 5
// baseline (1069.449 us; speedup 1.0000x reference)
//
#include <hip/hip_runtime.h>
#include <hip/hip_bf16.h>
#include <cstdint>
#include <cstddef>

// Problem constants
#define KDIM  16384          // batch (reduction dim of gram)
#define CNUM  2048           // classes
#define NROW  4096           // 2*CNUM
#define BK    32             // K-step per staged tile
#define NT    (KDIM / BK)    // 512 K-iterations

typedef __attribute__((ext_vector_type(8))) short bf16x8;
typedef __attribute__((ext_vector_type(4))) float f32x4;

// ---------------------------------------------------------------------------
// Kernel 1: transpose fp32 [B][C] -> bf16 Q [N][B], fused column sum / sumsq
// ---------------------------------------------------------------------------
__global__ __launch_bounds__(256) void transpose_sums_kernel(
    const float* __restrict__ qi, const float* __restrict__ qj,
    ushort* __restrict__ Qbf, float* __restrict__ p, float* __restrict__ sq)
{
    __shared__ float tile[64][68];   // 68 pad: keeps float4 LDS alignment, ~4-way ok
    const int tid = threadIdx.x;
    const int tt  = blockIdx.x;      // 0..255  (t-tile)
    const int at  = blockIdx.y;      // 0..63   (a-tile)
    const int t0  = tt * 64;
    const float* src = (at < 32) ? qi : qj;
    const int c0 = (at < 32 ? at : at - 32) * 64;

    // read 64x64 floats, coalesced along c
    {
        const int tl = tid >> 2;           // row within tile (t)
        const int cl = (tid & 3) * 16;     // col start (c)
        const float* s = src + (size_t)(t0 + tl) * CNUM + c0 + cl;
        float4 v0 = *(const float4*)(s);
        float4 v1 = *(const float4*)(s + 4);
        float4 v2 = *(const float4*)(s + 8);
        float4 v3 = *(const float4*)(s + 12);
        *(float4*)&tile[tl][cl]      = v0;
        *(float4*)&tile[tl][cl + 4]  = v1;
        *(float4*)&tile[tl][cl + 8]  = v2;
        *(float4*)&tile[tl][cl + 12] = v3;
    }
    __syncthreads();

    // write transposed bf16, coalesced along t; fuse column sums
    const int al   = tid >> 2;   // 0..63 (a within tile)
    const int tseg = tid & 3;    // 0..3  (16-t segment)
    float s1 = 0.f, s2 = 0.f;
    ushort outv[16] __attribute__((aligned(16)));
#pragma unroll
    for (int k = 0; k < 16; ++k) {
        float v = tile[tseg * 16 + k][al];
        s1 += v; s2 += v * v;
        __hip_bfloat16 h = __float2bfloat16(v);
        outv[k] = *(ushort*)&h;
    }
    const size_t dst = (size_t)(at * 64 + al) * KDIM + t0 + tseg * 16;
    *(uint4*)(Qbf + dst)     = *(uint4*)&outv[0];
    *(uint4*)(Qbf + dst + 8) = *(uint4*)&outv[8];

    // combine the 4 tsegs of one column in-wave, then 1 atomic each
    s1 += __shfl_xor(s1, 1); s1 += __shfl_xor(s1, 2);
    s2 += __shfl_xor(s2, 1); s2 += __shfl_xor(s2, 2);
    if (tseg == 0) {
        atomicAdd(&p[at * 64 + al], s1);
        atomicAdd(&sq[at * 64 + al], s2);
    }
}

// ---------------------------------------------------------------------------
// Kernel 2: rnorm[a] = 1/sqrt(sumsq[a])
// ---------------------------------------------------------------------------
__global__ void rnorm_kernel(const float* __restrict__ sq, float* __restrict__ rnorm)
{
    int a = blockIdx.x * 256 + threadIdx.x;
    if (a < NROW) rnorm[a] = 1.0f / sqrtf(fmaxf(sq[a], 1e-30f));
}

// ---------------------------------------------------------------------------
// Kernel 3: 128x128-tile gram via mfma_f32_16x16x32_bf16, double-buffered
// global_load_lds staging; epilogue does sim scaling, diag mask, pos record,
// and per-row (max, sumexp) partials per 64-column chunk.
// ---------------------------------------------------------------------------
__global__ __launch_bounds__(256) void gram_lse_kernel(
    const ushort* __restrict__ Q, const float* __restrict__ rnorm,
    float* __restrict__ pM, float* __restrict__ pS, float* __restrict__ pos)
{
    __shared__ ushort lds[2][2][128][BK];   // [buf][A/B][row][k]  = 32 KiB

    const int tid  = threadIdx.x;
    const int lane = tid & 63;
    const int wid  = tid >> 6;          // 0..3
    const int wr   = wid >> 1;          // wave row (0..1)  -> 64 rows
    const int wc   = wid & 1;           // wave col (0..1)  -> 64 cols
    const int g    = lane >> 4;         // k-group 0..3
    const int c15  = lane & 15;
    const int I = blockIdx.y, J = blockIdx.x;
    const int Ibase = I * 128, Jbase = J * 128;

    auto stage = [&](int buf, int kt) {
        const int k0 = kt * BK;
        const int rsub = lane >> 2;           // 0..15 row within chunk
        const int kk   = (lane & 3) * 8;      // k element offset
#pragma unroll
        for (int q2 = 0; q2 < 2; ++q2) {
            const int chunk = wid * 2 + q2;   // 0..7 (16 rows each)
            const ushort* ga = Q + (size_t)(Ibase + chunk * 16 + rsub) * KDIM + k0 + kk;
            __builtin_amdgcn_global_load_lds(
                (const __attribute__((address_space(1))) void*)ga,
                (__attribute__((address_space(3))) void*)&lds[buf][0][chunk * 16][0],
                16, 0, 0);
            const ushort* gb = Q + (size_t)(Jbase + chunk * 16 + rsub) * KDIM + k0 + kk;
            __builtin_amdgcn_global_load_lds(
                (const __attribute__((address_space(1))) void*)gb,
                (__attribute__((address_space(3))) void*)&lds[buf][1][chunk * 16][0],
                16, 0, 0);
        }
    };

    f32x4 acc[4][4] = {};

    stage(0, 0);
    __syncthreads();             // compiler drains vmcnt before barrier
    int cur = 0;
    for (int kt = 0; kt < NT; ++kt) {
        if (kt + 1 < NT) stage(cur ^ 1, kt + 1);
        bf16x8 af[4], bfr[4];
#pragma unroll
        for (int m = 0; m < 4; ++m)
            af[m] = *(const bf16x8*)&lds[cur][0][wr * 64 + m * 16 + c15][g * 8];
#pragma unroll
        for (int n = 0; n < 4; ++n)
            bfr[n] = *(const bf16x8*)&lds[cur][1][wc * 64 + n * 16 + c15][g * 8];
#pragma unroll
        for (int m = 0; m < 4; ++m)
#pragma unroll
            for (int n = 0; n < 4; ++n)
                acc[m][n] = __builtin_amdgcn_mfma_f32_16x16x32_bf16(af[m], bfr[n], acc[m][n], 0, 0, 0);
        __syncthreads();
        cur ^= 1;
    }

    // ---- epilogue ----
    float rb[4], ra[4][4];
#pragma unroll
    for (int n = 0; n < 4; ++n) rb[n] = rnorm[Jbase + wc * 64 + n * 16 + c15];
#pragma unroll
    for (int m = 0; m < 4; ++m)
#pragma unroll
        for (int r = 0; r < 4; ++r)
            ra[m][r] = rnorm[Ibase + wr * 64 + m * 16 + g * 4 + r];

    const bool diagT = (I == J);
    const bool posT  = (J == (I ^ 16));   // partner block (offset +-C)
#pragma unroll
    for (int m = 0; m < 4; ++m) {
#pragma unroll
        for (int n = 0; n < 4; ++n) {
#pragma unroll
            for (int r = 0; r < 4; ++r) {
                float sv = acc[m][n][r] * ra[m][r] * rb[n];
                const int aoff = wr * 64 + m * 16 + g * 4 + r;
                const int boff = wc * 64 + n * 16 + c15;
                if (posT && aoff == boff) pos[Ibase + aoff] = sv;
                if (diagT && aoff == boff) sv = -1e30f;   // exclude b == a
                acc[m][n][r] = sv;
            }
        }
    }

    // per-row max and sum(exp) over this wave's 64 columns
#pragma unroll
    for (int m = 0; m < 4; ++m) {
#pragma unroll
        for (int r = 0; r < 4; ++r) {
            float mx = fmaxf(fmaxf(acc[m][0][r], acc[m][1][r]),
                             fmaxf(acc[m][2][r], acc[m][3][r]));
#pragma unroll
            for (int d = 8; d >= 1; d >>= 1) mx = fmaxf(mx, __shfl_xor(mx, d));
            float s = 0.f;
#pragma unroll
            for (int n = 0; n < 4; ++n) s += __expf(acc[m][n][r] - mx);
#pragma unroll
            for (int d = 8; d >= 1; d >>= 1) s += __shfl_xor(s, d);
            if (c15 == 0) {
                const int a  = Ibase + wr * 64 + m * 16 + g * 4 + r;
                const int Jc = J * 2 + wc;   // 64 column chunks
                pM[(size_t)Jc * NROW + a] = mx;
                pS[(size_t)Jc * NROW + a] = s;
            }
        }
    }
}

// ---------------------------------------------------------------------------
// Kernel 4: combine 64 partials per row -> lse, ce = lse - pos; sum ce
// ---------------------------------------------------------------------------
__global__ __launch_bounds__(256) void combine_kernel(
    const float* __restrict__ pM, const float* __restrict__ pS,
    const float* __restrict__ pos, float* __restrict__ ce_acc)
{
    const int a = blockIdx.x * 256 + threadIdx.x;   // grid 16 -> 4096 rows
    float mx = -1e30f;
#pragma unroll 8
    for (int j = 0; j < 64; ++j) mx = fmaxf(mx, pM[(size_t)j * NROW + a]);
    float s = 0.f;
#pragma unroll 8
    for (int j = 0; j < 64; ++j)
        s += pS[(size_t)j * NROW + a] * __expf(pM[(size_t)j * NROW + a] - mx);
    float ce = mx + logf(s) - pos[a];

    // block reduce
    float v = ce;
#pragma unroll
    for (int d = 32; d >= 1; d >>= 1) v += __shfl_xor(v, d);
    __shared__ float red[4];
    if ((threadIdx.x & 63) == 0) red[threadIdx.x >> 6] = v;
    __syncthreads();
    if (threadIdx.x == 0)
        atomicAdd(ce_acc, red[0] + red[1] + red[2] + red[3]);
}

// ---------------------------------------------------------------------------
// Kernel 5: entropy terms + final scalar
// ---------------------------------------------------------------------------
__global__ __launch_bounds__(256) void finalize_kernel(
    const float* __restrict__ p, const float* __restrict__ ce_acc,
    float* __restrict__ out)
{
    const int tid = threadIdx.x;
    float spi = 0.f, spli = 0.f, spj = 0.f, splj = 0.f;
    for (int c = tid; c < CNUM; c += 256) {
        float v = p[c];        spi += v; spli += v * logf(v);
        float w = p[CNUM + c]; spj += w; splj += w * logf(w);
    }
#pragma unroll
    for (int d = 32; d >= 1; d >>= 1) {
        spi  += __shfl_xor(spi, d);  spli += __shfl_xor(spli, d);
        spj  += __shfl_xor(spj, d);  splj += __shfl_xor(splj, d);
    }
    __shared__ float r4[4][4];
    if ((tid & 63) == 0) {
        int w = tid >> 6;
        r4[w][0] = spi; r4[w][1] = spli; r4[w][2] = spj; r4[w][3] = splj;
    }
    __syncthreads();
    if (tid == 0) {
        spi  = r4[0][0] + r4[1][0] + r4[2][0] + r4[3][0];
        spli = r4[0][1] + r4[1][1] + r4[2][1] + r4[3][1];
        spj  = r4[0][2] + r4[1][2] + r4[2][2] + r4[3][2];
        splj = r4[0][3] + r4[1][3] + r4[2][3] + r4[3][3];
        float nei = logf((float)CNUM) + spli / spi - logf(spi);
        float nej = logf((float)CNUM) + splj / spj - logf(spj);
        out[0] = ce_acc[0] / (float)NROW + nei + nej;
    }
}

// ---------------------------------------------------------------------------
extern "C" void kernel_launch(void* const* d_in, const int* in_sizes, int n_in,
                              void* d_out, int out_size, void* d_ws, size_t ws_size,
                              hipStream_t stream)
{
    const float* qi = (const float*)d_in[0];
    const float* qj = (const float*)d_in[1];
    float* out = (float*)d_out;

    char* ws = (char*)d_ws;
    const size_t QB = (size_t)NROW * KDIM * sizeof(ushort);   // 128 MiB
    ushort* Qbf  = (ushort*)ws;
    float* p     = (float*)(ws + QB);                  // 16 KiB
    float* sq    = (float*)(ws + QB + 16384);          // 16 KiB
    float* ce    = (float*)(ws + QB + 32768);          // 4 B (zeroed)
    float* rnorm = (float*)(ws + QB + 33024);          // 16 KiB
    float* pos   = (float*)(ws + QB + 49408);          // 16 KiB
    float* pM    = (float*)(ws + QB + 65792);          // 1 MiB
    float* pS    = (float*)(ws + QB + 65792 + 1048576);// 1 MiB

    // zero the atomic accumulators (p, sq, ce) — ws is poisoned 0xAA each run
    hipMemsetAsync(ws + QB, 0, 33024, stream);

    dim3 gT(256, 64);
    transpose_sums_kernel<<<gT, 256, 0, stream>>>(qi, qj, Qbf, p, sq);
    rnorm_kernel<<<16, 256, 0, stream>>>(sq, rnorm);
    dim3 gG(32, 32);
    gram_lse_kernel<<<gG, 256, 0, stream>>>(Qbf, rnorm, pM, pS, pos);
    combine_kernel<<<16, 256, 0, stream>>>(pM, pS, pos, ce);
    finalize_kernel<<<1, 256, 0, stream>>>(p, ce, out);
}

// Round 8
// 816.798 us; speedup vs baseline: 1.3093x; 1.3093x over previous
//
#include <hip/hip_runtime.h>
#include <hip/hip_bf16.h>
#include <cstdint>
#include <cstddef>

// Problem constants
#define KDIM  16384          // batch (reduction dim of gram)
#define CNUM  2048           // classes
#define NROW  4096           // 2*CNUM
#define BM    256            // gram tile (256x256)
#define BK    32             // K-step per staged tile
#define NT    (KDIM / BK)    // 512 K-iterations

typedef __attribute__((ext_vector_type(8))) short bf16x8;
typedef __attribute__((ext_vector_type(4))) float f32x4;

// ---------------------------------------------------------------------------
// Kernel 1: transpose fp32 [B][C] -> bf16 Q [N][B], fused column sum / sumsq
// ---------------------------------------------------------------------------
__global__ __launch_bounds__(256) void transpose_sums_kernel(
    const float* __restrict__ qi, const float* __restrict__ qj,
    ushort* __restrict__ Qbf, float* __restrict__ p, float* __restrict__ sq)
{
    __shared__ float tile[64][68];
    const int tid = threadIdx.x;
    const int tt  = blockIdx.x;      // 0..255  (t-tile)
    const int at  = blockIdx.y;      // 0..63   (a-tile)
    const int t0  = tt * 64;
    const float* src = (at < 32) ? qi : qj;
    const int c0 = (at < 32 ? at : at - 32) * 64;

    {
        const int tl = tid >> 2;
        const int cl = (tid & 3) * 16;
        const float* s = src + (size_t)(t0 + tl) * CNUM + c0 + cl;
        float4 v0 = *(const float4*)(s);
        float4 v1 = *(const float4*)(s + 4);
        float4 v2 = *(const float4*)(s + 8);
        float4 v3 = *(const float4*)(s + 12);
        *(float4*)&tile[tl][cl]      = v0;
        *(float4*)&tile[tl][cl + 4]  = v1;
        *(float4*)&tile[tl][cl + 8]  = v2;
        *(float4*)&tile[tl][cl + 12] = v3;
    }
    __syncthreads();

    const int al   = tid >> 2;
    const int tseg = tid & 3;
    float s1 = 0.f, s2 = 0.f;
    ushort outv[16] __attribute__((aligned(16)));
#pragma unroll
    for (int k = 0; k < 16; ++k) {
        float v = tile[tseg * 16 + k][al];
        s1 += v; s2 += v * v;
        __hip_bfloat16 h = __float2bfloat16(v);
        outv[k] = *(ushort*)&h;
    }
    const size_t dst = (size_t)(at * 64 + al) * KDIM + t0 + tseg * 16;
    *(uint4*)(Qbf + dst)     = *(uint4*)&outv[0];
    *(uint4*)(Qbf + dst + 8) = *(uint4*)&outv[8];

    s1 += __shfl_xor(s1, 1); s1 += __shfl_xor(s1, 2);
    s2 += __shfl_xor(s2, 1); s2 += __shfl_xor(s2, 2);
    if (tseg == 0) {
        atomicAdd(&p[at * 64 + al], s1);
        atomicAdd(&sq[at * 64 + al], s2);
    }
}

// ---------------------------------------------------------------------------
// Kernel 2: rnorm[a] = 1/sqrt(sumsq[a])
// ---------------------------------------------------------------------------
__global__ void rnorm_kernel(const float* __restrict__ sq, float* __restrict__ rnorm)
{
    int a = blockIdx.x * 256 + threadIdx.x;
    if (a < NROW) rnorm[a] = 1.0f / sqrtf(fmaxf(sq[a], 1e-30f));
}

// ---------------------------------------------------------------------------
// Kernel 3: 256x256-tile gram, 8 waves, mfma_f32_16x16x32_bf16, double-buffered
// global_load_lds staging (hoisted pointers); epilogue: sim scaling, diag mask,
// pos record, per-row (max, sumexp) partials per 64-col chunk.
// Per wave: 128x64 output = acc[8][4] fragments.
// ---------------------------------------------------------------------------
__global__ __launch_bounds__(512) void gram_lse_kernel(
    const ushort* __restrict__ Q, const float* __restrict__ rnorm,
    float* __restrict__ pM, float* __restrict__ pS, float* __restrict__ pos)
{
    __shared__ ushort lds[2][2][BM][BK];   // [buf][A/B][row][k] = 64 KiB

    const int tid  = threadIdx.x;
    const int lane = tid & 63;
    const int wid  = tid >> 6;          // 0..7
    const int wr   = wid >> 2;          // 0..1  -> 128-row half
    const int wc   = wid & 3;           // 0..3  -> 64-col quarter
    const int g    = lane >> 4;         // k-group 0..3
    const int c15  = lane & 15;
    const int I = blockIdx.y, J = blockIdx.x;
    const int Ibase = I * BM, Jbase = J * BM;

    // Hoisted global stage pointers. Per K-step each thread issues 4
    // global_load_lds (2 row-rounds x {A,B}); round r covers rows r*128 +
    // wid*16 + (lane>>2), k-offset (lane&3)*8 == linear lane*16B in LDS.
    const int srow = tid >> 2;          // 0..127 (== wid*16 + (lane>>2))
    const int skk  = (tid & 3) * 8;
    const ushort* gA0 = Q + (size_t)(Ibase + srow) * KDIM + skk;
    const ushort* gA1 = Q + (size_t)(Ibase + 128 + srow) * KDIM + skk;
    const ushort* gB0 = Q + (size_t)(Jbase + srow) * KDIM + skk;
    const ushort* gB1 = Q + (size_t)(Jbase + 128 + srow) * KDIM + skk;

    auto stage = [&](int buf, int kt) {
        const int k0 = kt * BK;
        __builtin_amdgcn_global_load_lds(
            (const __attribute__((address_space(1))) void*)(gA0 + k0),
            (__attribute__((address_space(3))) void*)&lds[buf][0][wid * 16][0],
            16, 0, 0);
        __builtin_amdgcn_global_load_lds(
            (const __attribute__((address_space(1))) void*)(gA1 + k0),
            (__attribute__((address_space(3))) void*)&lds[buf][0][128 + wid * 16][0],
            16, 0, 0);
        __builtin_amdgcn_global_load_lds(
            (const __attribute__((address_space(1))) void*)(gB0 + k0),
            (__attribute__((address_space(3))) void*)&lds[buf][1][wid * 16][0],
            16, 0, 0);
        __builtin_amdgcn_global_load_lds(
            (const __attribute__((address_space(1))) void*)(gB1 + k0),
            (__attribute__((address_space(3))) void*)&lds[buf][1][128 + wid * 16][0],
            16, 0, 0);
    };

    f32x4 acc[8][4] = {};

    stage(0, 0);
    __syncthreads();             // vmcnt(0) drained at barrier
    int cur = 0;
    for (int kt = 0; kt < NT; ++kt) {
        if (kt + 1 < NT) stage(cur ^ 1, kt + 1);
        bf16x8 bfr[4], af[8];
#pragma unroll
        for (int n = 0; n < 4; ++n)
            bfr[n] = *(const bf16x8*)&lds[cur][1][wc * 64 + n * 16 + c15][g * 8];
#pragma unroll
        for (int m = 0; m < 8; ++m)
            af[m] = *(const bf16x8*)&lds[cur][0][wr * 128 + m * 16 + c15][g * 8];
#pragma unroll
        for (int m = 0; m < 8; ++m)
#pragma unroll
            for (int n = 0; n < 4; ++n)
                acc[m][n] = __builtin_amdgcn_mfma_f32_16x16x32_bf16(af[m], bfr[n], acc[m][n], 0, 0, 0);
        __syncthreads();
        cur ^= 1;
    }

    // ---- epilogue ----
    float rb[4], ra[8][4];
#pragma unroll
    for (int n = 0; n < 4; ++n) rb[n] = rnorm[Jbase + wc * 64 + n * 16 + c15];
#pragma unroll
    for (int m = 0; m < 8; ++m)
#pragma unroll
        for (int r = 0; r < 4; ++r)
            ra[m][r] = rnorm[Ibase + wr * 128 + m * 16 + g * 4 + r];

    const bool diagT = (I == J);
    const bool posT  = (J == (I ^ 8));   // partner tile (offset +-C = 8 tiles)
#pragma unroll
    for (int m = 0; m < 8; ++m) {
#pragma unroll
        for (int n = 0; n < 4; ++n) {
#pragma unroll
            for (int r = 0; r < 4; ++r) {
                float sv = acc[m][n][r] * ra[m][r] * rb[n];
                const int aoff = wr * 128 + m * 16 + g * 4 + r;
                const int boff = wc * 64 + n * 16 + c15;
                if (posT && aoff == boff) pos[Ibase + aoff] = sv;
                if (diagT && aoff == boff) sv = -1e30f;   // exclude b == a
                acc[m][n][r] = sv;
            }
        }
    }

    // per-row max and sum(exp) over this wave's 64 columns
#pragma unroll
    for (int m = 0; m < 8; ++m) {
#pragma unroll
        for (int r = 0; r < 4; ++r) {
            float mx = fmaxf(fmaxf(acc[m][0][r], acc[m][1][r]),
                             fmaxf(acc[m][2][r], acc[m][3][r]));
#pragma unroll
            for (int d = 8; d >= 1; d >>= 1) mx = fmaxf(mx, __shfl_xor(mx, d));
            float s = 0.f;
#pragma unroll
            for (int n = 0; n < 4; ++n) s += __expf(acc[m][n][r] - mx);
#pragma unroll
            for (int d = 8; d >= 1; d >>= 1) s += __shfl_xor(s, d);
            if (c15 == 0) {
                const int a  = Ibase + wr * 128 + m * 16 + g * 4 + r;
                const int Jc = J * 4 + wc;   // 64 column chunks of 64
                pM[(size_t)Jc * NROW + a] = mx;
                pS[(size_t)Jc * NROW + a] = s;
            }
        }
    }
}

// ---------------------------------------------------------------------------
// Kernel 4: combine 64 partials per row -> lse, ce = lse - pos; sum ce
// ---------------------------------------------------------------------------
__global__ __launch_bounds__(256) void combine_kernel(
    const float* __restrict__ pM, const float* __restrict__ pS,
    const float* __restrict__ pos, float* __restrict__ ce_acc)
{
    const int a = blockIdx.x * 256 + threadIdx.x;   // grid 16 -> 4096 rows
    float mx = -1e30f;
#pragma unroll 8
    for (int j = 0; j < 64; ++j) mx = fmaxf(mx, pM[(size_t)j * NROW + a]);
    float s = 0.f;
#pragma unroll 8
    for (int j = 0; j < 64; ++j)
        s += pS[(size_t)j * NROW + a] * __expf(pM[(size_t)j * NROW + a] - mx);
    float ce = mx + logf(s) - pos[a];

    float v = ce;
#pragma unroll
    for (int d = 32; d >= 1; d >>= 1) v += __shfl_xor(v, d);
    __shared__ float red[4];
    if ((threadIdx.x & 63) == 0) red[threadIdx.x >> 6] = v;
    __syncthreads();
    if (threadIdx.x == 0)
        atomicAdd(ce_acc, red[0] + red[1] + red[2] + red[3]);
}

// ---------------------------------------------------------------------------
// Kernel 5: entropy terms + final scalar
// ---------------------------------------------------------------------------
__global__ __launch_bounds__(256) void finalize_kernel(
    const float* __restrict__ p, const float* __restrict__ ce_acc,
    float* __restrict__ out)
{
    const int tid = threadIdx.x;
    float spi = 0.f, spli = 0.f, spj = 0.f, splj = 0.f;
    for (int c = tid; c < CNUM; c += 256) {
        float v = p[c];        spi += v; spli += v * logf(v);
        float w = p[CNUM + c]; spj += w; splj += w * logf(w);
    }
#pragma unroll
    for (int d = 32; d >= 1; d >>= 1) {
        spi  += __shfl_xor(spi, d);  spli += __shfl_xor(spli, d);
        spj  += __shfl_xor(spj, d);  splj += __shfl_xor(splj, d);
    }
    __shared__ float r4[4][4];
    if ((tid & 63) == 0) {
        int w = tid >> 6;
        r4[w][0] = spi; r4[w][1] = spli; r4[w][2] = spj; r4[w][3] = splj;
    }
    __syncthreads();
    if (tid == 0) {
        spi  = r4[0][0] + r4[1][0] + r4[2][0] + r4[3][0];
        spli = r4[0][1] + r4[1][1] + r4[2][1] + r4[3][1];
        spj  = r4[0][2] + r4[1][2] + r4[2][2] + r4[3][2];
        splj = r4[0][3] + r4[1][3] + r4[2][3] + r4[3][3];
        float nei = logf((float)CNUM) + spli / spi - logf(spi);
        float nej = logf((float)CNUM) + splj / spj - logf(spj);
        out[0] = ce_acc[0] / (float)NROW + nei + nej;
    }
}

// ---------------------------------------------------------------------------
extern "C" void kernel_launch(void* const* d_in, const int* in_sizes, int n_in,
                              void* d_out, int out_size, void* d_ws, size_t ws_size,
                              hipStream_t stream)
{
    const float* qi = (const float*)d_in[0];
    const float* qj = (const float*)d_in[1];
    float* out = (float*)d_out;

    char* ws = (char*)d_ws;
    const size_t QB = (size_t)NROW * KDIM * sizeof(ushort);   // 128 MiB
    ushort* Qbf  = (ushort*)ws;
    float* p     = (float*)(ws + QB);                  // 16 KiB
    float* sq    = (float*)(ws + QB + 16384);          // 16 KiB
    float* ce    = (float*)(ws + QB + 32768);          // 4 B (zeroed)
    float* rnorm = (float*)(ws + QB + 33024);          // 16 KiB
    float* pos   = (float*)(ws + QB + 49408);          // 16 KiB
    float* pM    = (float*)(ws + QB + 65792);          // 1 MiB
    float* pS    = (float*)(ws + QB + 65792 + 1048576);// 1 MiB

    // zero the atomic accumulators (p, sq, ce) — ws is poisoned 0xAA each run
    hipMemsetAsync(ws + QB, 0, 33024, stream);

    dim3 gT(256, 64);
    transpose_sums_kernel<<<gT, 256, 0, stream>>>(qi, qj, Qbf, p, sq);
    rnorm_kernel<<<16, 256, 0, stream>>>(sq, rnorm);
    dim3 gG(16, 16);
    gram_lse_kernel<<<gG, 512, 0, stream>>>(Qbf, rnorm, pM, pS, pos);
    combine_kernel<<<16, 256, 0, stream>>>(pM, pS, pos, ce);
    finalize_kernel<<<1, 256, 0, stream>>>(p, ce, out);
}

// Round 9
// 726.705 us; speedup vs baseline: 1.4716x; 1.1240x over previous
//
#include <hip/hip_runtime.h>
#include <hip/hip_bf16.h>
#include <cstdint>
#include <cstddef>

// Problem constants
#define KDIM  16384          // batch (reduction dim of gram)
#define CNUM  2048           // classes
#define NROW  4096           // 2*CNUM
#define BM    256            // gram tile (256x256)
#define BK    64             // K-step per staged tile (2 MFMA k-slices)
#define NT    (KDIM / BK)    // 256 K-iterations

typedef __attribute__((ext_vector_type(8))) short bf16x8;
typedef __attribute__((ext_vector_type(4))) float f32x4;

// ---------------------------------------------------------------------------
// Kernel 1: transpose fp32 [B][C] -> bf16 Q [N][B], fused column sum / sumsq
// ---------------------------------------------------------------------------
__global__ __launch_bounds__(256) void transpose_sums_kernel(
    const float* __restrict__ qi, const float* __restrict__ qj,
    ushort* __restrict__ Qbf, float* __restrict__ p, float* __restrict__ sq)
{
    __shared__ float tile[64][68];
    const int tid = threadIdx.x;
    const int tt  = blockIdx.x;      // 0..255  (t-tile)
    const int at  = blockIdx.y;      // 0..63   (a-tile)
    const int t0  = tt * 64;
    const float* src = (at < 32) ? qi : qj;
    const int c0 = (at < 32 ? at : at - 32) * 64;

    {
        const int tl = tid >> 2;
        const int cl = (tid & 3) * 16;
        const float* s = src + (size_t)(t0 + tl) * CNUM + c0 + cl;
        float4 v0 = *(const float4*)(s);
        float4 v1 = *(const float4*)(s + 4);
        float4 v2 = *(const float4*)(s + 8);
        float4 v3 = *(const float4*)(s + 12);
        *(float4*)&tile[tl][cl]      = v0;
        *(float4*)&tile[tl][cl + 4]  = v1;
        *(float4*)&tile[tl][cl + 8]  = v2;
        *(float4*)&tile[tl][cl + 12] = v3;
    }
    __syncthreads();

    const int al   = tid >> 2;
    const int tseg = tid & 3;
    float s1 = 0.f, s2 = 0.f;
    ushort outv[16] __attribute__((aligned(16)));
#pragma unroll
    for (int k = 0; k < 16; ++k) {
        float v = tile[tseg * 16 + k][al];
        s1 += v; s2 += v * v;
        __hip_bfloat16 h = __float2bfloat16(v);
        outv[k] = *(ushort*)&h;
    }
    const size_t dst = (size_t)(at * 64 + al) * KDIM + t0 + tseg * 16;
    *(uint4*)(Qbf + dst)     = *(uint4*)&outv[0];
    *(uint4*)(Qbf + dst + 8) = *(uint4*)&outv[8];

    s1 += __shfl_xor(s1, 1); s1 += __shfl_xor(s1, 2);
    s2 += __shfl_xor(s2, 1); s2 += __shfl_xor(s2, 2);
    if (tseg == 0) {
        atomicAdd(&p[at * 64 + al], s1);
        atomicAdd(&sq[at * 64 + al], s2);
    }
}

// ---------------------------------------------------------------------------
// Kernel 2: rnorm[a] = 1/sqrt(sumsq[a])
// ---------------------------------------------------------------------------
__global__ void rnorm_kernel(const float* __restrict__ sq, float* __restrict__ rnorm)
{
    int a = blockIdx.x * 256 + threadIdx.x;
    if (a < NROW) rnorm[a] = 1.0f / sqrtf(fmaxf(sq[a], 1e-30f));
}

// ---------------------------------------------------------------------------
// Kernel 3: 256x256-tile gram, BK=64, 8 waves, mfma_f32_16x16x32_bf16.
// Double-buffered global_load_lds staging with XOR-swizzled 16B segments:
//   LDS physical slot s of row r holds global k-segment s ^ (r&7)
//   (linear LDS dest, inverse-swizzled global source, swizzled read — rule 21).
// Epilogue: sim scaling, diag mask, pos record, per-row (max,sumexp) partials.
// Dynamic LDS: 2 bufs x 2 ops x 256 rows x 64 ushort = 128 KiB.
// ---------------------------------------------------------------------------
__global__ __launch_bounds__(512) void gram_lse_kernel(
    const ushort* __restrict__ Q, const float* __restrict__ rnorm,
    float* __restrict__ pM, float* __restrict__ pS, float* __restrict__ pos)
{
    extern __shared__ ushort L[];   // [buf][op][256][64]

    const int tid  = threadIdx.x;
    const int lane = tid & 63;
    const int wid  = tid >> 6;          // 0..7
    const int wr   = wid >> 2;          // 0..1  -> 128-row half
    const int wc   = wid & 3;           // 0..3  -> 64-col quarter
    const int g    = lane >> 4;         // k-group 0..3
    const int c15  = lane & 15;
    const int I = blockIdx.y, J = blockIdx.x;
    const int Ibase = I * BM, Jbase = J * BM;

    // Staging geometry: per round q (0..3) per operand, wave wid covers rows
    // q*64 + wid*8 .. +8, each row = 8 segments of 16B; lane l -> row offset
    // l>>3, physical slot l&7, global segment (l&7)^(l>>3) (XOR swizzle).
    const int r8 = lane >> 3;           // 0..7
    const int sseg = (lane & 7) ^ r8;   // inverse-swizzled global segment
    const ushort* gA[4];
    const ushort* gB[4];
#pragma unroll
    for (int q = 0; q < 4; ++q) {
        const int row = q * 64 + wid * 8 + r8;
        gA[q] = Q + (size_t)(Ibase + row) * KDIM + sseg * 8;
        gB[q] = Q + (size_t)(Jbase + row) * KDIM + sseg * 8;
    }

    auto stage = [&](int buf, int kt) {
        const int k0 = kt * BK;
#pragma unroll
        for (int q = 0; q < 4; ++q) {
            __builtin_amdgcn_global_load_lds(
                (const __attribute__((address_space(1))) void*)(gA[q] + k0),
                (__attribute__((address_space(3))) void*)&L[((buf * 2 + 0) * 256 + q * 64 + wid * 8) * 64],
                16, 0, 0);
            __builtin_amdgcn_global_load_lds(
                (const __attribute__((address_space(1))) void*)(gB[q] + k0),
                (__attribute__((address_space(3))) void*)&L[((buf * 2 + 1) * 256 + q * 64 + wid * 8) * 64],
                16, 0, 0);
        }
    };

    f32x4 acc[8][4] = {};

    stage(0, 0);
    __syncthreads();             // vmcnt(0) drained at barrier
    int cur = 0;
    for (int kt = 0; kt < NT; ++kt) {
        if (kt + 1 < NT) stage(cur ^ 1, kt + 1);
#pragma unroll
        for (int kh = 0; kh < 2; ++kh) {
            // swizzled read: slot = (kh*4+g) ^ (row&7), row&7 == c15&7
            const int slot = ((kh << 2) | g) ^ (c15 & 7);
            bf16x8 bfr[4], af[8];
#pragma unroll
            for (int n = 0; n < 4; ++n)
                bfr[n] = *(const bf16x8*)&L[((cur * 2 + 1) * 256 + wc * 64 + n * 16 + c15) * 64 + slot * 8];
#pragma unroll
            for (int m = 0; m < 8; ++m)
                af[m] = *(const bf16x8*)&L[((cur * 2 + 0) * 256 + wr * 128 + m * 16 + c15) * 64 + slot * 8];
#pragma unroll
            for (int m = 0; m < 8; ++m)
#pragma unroll
                for (int n = 0; n < 4; ++n)
                    acc[m][n] = __builtin_amdgcn_mfma_f32_16x16x32_bf16(af[m], bfr[n], acc[m][n], 0, 0, 0);
        }
        __syncthreads();
        cur ^= 1;
    }

    // ---- epilogue ----
    float rb[4], ra[8][4];
#pragma unroll
    for (int n = 0; n < 4; ++n) rb[n] = rnorm[Jbase + wc * 64 + n * 16 + c15];
#pragma unroll
    for (int m = 0; m < 8; ++m)
#pragma unroll
        for (int r = 0; r < 4; ++r)
            ra[m][r] = rnorm[Ibase + wr * 128 + m * 16 + g * 4 + r];

    const bool diagT = (I == J);
    const bool posT  = (J == (I ^ 8));   // partner tile (offset +-C = 8 tiles)
#pragma unroll
    for (int m = 0; m < 8; ++m) {
#pragma unroll
        for (int n = 0; n < 4; ++n) {
#pragma unroll
            for (int r = 0; r < 4; ++r) {
                float sv = acc[m][n][r] * ra[m][r] * rb[n];
                const int aoff = wr * 128 + m * 16 + g * 4 + r;
                const int boff = wc * 64 + n * 16 + c15;
                if (posT && aoff == boff) pos[Ibase + aoff] = sv;
                if (diagT && aoff == boff) sv = -1e30f;   // exclude b == a
                acc[m][n][r] = sv;
            }
        }
    }

    // per-row max and sum(exp) over this wave's 64 columns
#pragma unroll
    for (int m = 0; m < 8; ++m) {
#pragma unroll
        for (int r = 0; r < 4; ++r) {
            float mx = fmaxf(fmaxf(acc[m][0][r], acc[m][1][r]),
                             fmaxf(acc[m][2][r], acc[m][3][r]));
#pragma unroll
            for (int d = 8; d >= 1; d >>= 1) mx = fmaxf(mx, __shfl_xor(mx, d));
            float s = 0.f;
#pragma unroll
            for (int n = 0; n < 4; ++n) s += __expf(acc[m][n][r] - mx);
#pragma unroll
            for (int d = 8; d >= 1; d >>= 1) s += __shfl_xor(s, d);
            if (c15 == 0) {
                const int a  = Ibase + wr * 128 + m * 16 + g * 4 + r;
                const int Jc = J * 4 + wc;   // 64 column chunks of 64
                pM[(size_t)Jc * NROW + a] = mx;
                pS[(size_t)Jc * NROW + a] = s;
            }
        }
    }
}

// ---------------------------------------------------------------------------
// Kernel 4: combine 64 partials per row -> lse, ce = lse - pos; sum ce
// ---------------------------------------------------------------------------
__global__ __launch_bounds__(256) void combine_kernel(
    const float* __restrict__ pM, const float* __restrict__ pS,
    const float* __restrict__ pos, float* __restrict__ ce_acc)
{
    const int a = blockIdx.x * 256 + threadIdx.x;   // grid 16 -> 4096 rows
    float mx = -1e30f;
#pragma unroll 8
    for (int j = 0; j < 64; ++j) mx = fmaxf(mx, pM[(size_t)j * NROW + a]);
    float s = 0.f;
#pragma unroll 8
    for (int j = 0; j < 64; ++j)
        s += pS[(size_t)j * NROW + a] * __expf(pM[(size_t)j * NROW + a] - mx);
    float ce = mx + logf(s) - pos[a];

    float v = ce;
#pragma unroll
    for (int d = 32; d >= 1; d >>= 1) v += __shfl_xor(v, d);
    __shared__ float red[4];
    if ((threadIdx.x & 63) == 0) red[threadIdx.x >> 6] = v;
    __syncthreads();
    if (threadIdx.x == 0)
        atomicAdd(ce_acc, red[0] + red[1] + red[2] + red[3]);
}

// ---------------------------------------------------------------------------
// Kernel 5: entropy terms + final scalar
// ---------------------------------------------------------------------------
__global__ __launch_bounds__(256) void finalize_kernel(
    const float* __restrict__ p, const float* __restrict__ ce_acc,
    float* __restrict__ out)
{
    const int tid = threadIdx.x;
    float spi = 0.f, spli = 0.f, spj = 0.f, splj = 0.f;
    for (int c = tid; c < CNUM; c += 256) {
        float v = p[c];        spi += v; spli += v * logf(v);
        float w = p[CNUM + c]; spj += w; splj += w * logf(w);
    }
#pragma unroll
    for (int d = 32; d >= 1; d >>= 1) {
        spi  += __shfl_xor(spi, d);  spli += __shfl_xor(spli, d);
        spj  += __shfl_xor(spj, d);  splj += __shfl_xor(splj, d);
    }
    __shared__ float r4[4][4];
    if ((tid & 63) == 0) {
        int w = tid >> 6;
        r4[w][0] = spi; r4[w][1] = spli; r4[w][2] = spj; r4[w][3] = splj;
    }
    __syncthreads();
    if (tid == 0) {
        spi  = r4[0][0] + r4[1][0] + r4[2][0] + r4[3][0];
        spli = r4[0][1] + r4[1][1] + r4[2][1] + r4[3][1];
        spj  = r4[0][2] + r4[1][2] + r4[2][2] + r4[3][2];
        splj = r4[0][3] + r4[1][3] + r4[2][3] + r4[3][3];
        float nei = logf((float)CNUM) + spli / spi - logf(spi);
        float nej = logf((float)CNUM) + splj / spj - logf(spj);
        out[0] = ce_acc[0] / (float)NROW + nei + nej;
    }
}

// ---------------------------------------------------------------------------
extern "C" void kernel_launch(void* const* d_in, const int* in_sizes, int n_in,
                              void* d_out, int out_size, void* d_ws, size_t ws_size,
                              hipStream_t stream)
{
    const float* qi = (const float*)d_in[0];
    const float* qj = (const float*)d_in[1];
    float* out = (float*)d_out;

    char* ws = (char*)d_ws;
    const size_t QB = (size_t)NROW * KDIM * sizeof(ushort);   // 128 MiB
    ushort* Qbf  = (ushort*)ws;
    float* p     = (float*)(ws + QB);                  // 16 KiB
    float* sq    = (float*)(ws + QB + 16384);          // 16 KiB
    float* ce    = (float*)(ws + QB + 32768);          // 4 B (zeroed)
    float* rnorm = (float*)(ws + QB + 33024);          // 16 KiB
    float* pos   = (float*)(ws + QB + 49408);          // 16 KiB
    float* pM    = (float*)(ws + QB + 65792);          // 1 MiB
    float* pS    = (float*)(ws + QB + 65792 + 1048576);// 1 MiB

    // allow 128 KiB dynamic LDS for the gram kernel (host-side, idempotent)
    hipFuncSetAttribute((const void*)gram_lse_kernel,
                        hipFuncAttributeMaxDynamicSharedMemorySize, 131072);

    // zero the atomic accumulators (p, sq, ce) — ws is poisoned 0xAA each run
    hipMemsetAsync(ws + QB, 0, 33024, stream);

    dim3 gT(256, 64);
    transpose_sums_kernel<<<gT, 256, 0, stream>>>(qi, qj, Qbf, p, sq);
    rnorm_kernel<<<16, 256, 0, stream>>>(sq, rnorm);
    dim3 gG(16, 16);
    gram_lse_kernel<<<gG, 512, 131072, stream>>>(Qbf, rnorm, pM, pS, pos);
    combine_kernel<<<16, 256, 0, stream>>>(pM, pS, pos, ce);
    finalize_kernel<<<1, 256, 0, stream>>>(p, ce, out);
}

// Round 10
// 720.613 us; speedup vs baseline: 1.4841x; 1.0085x over previous
//
#include <hip/hip_runtime.h>
#include <hip/hip_bf16.h>
#include <cstdint>
#include <cstddef>

// Problem constants
#define KDIM  16384          // batch (reduction dim of gram)
#define CNUM  2048           // classes
#define NROW  4096           // 2*CNUM
#define BM    256            // gram tile (256x256)
#define BK    64             // K-step per staged tile (2 MFMA k-slices)
#define NT    (KDIM / BK)    // 256 K-iterations

typedef __attribute__((ext_vector_type(8))) short bf16x8;
typedef __attribute__((ext_vector_type(4))) float f32x4;

// ---------------------------------------------------------------------------
// Kernel 1 (v2): transpose fp32 [B][C] -> bf16 Q [N][B], fused column sums.
// 64 a-cols x 128 t per block; LDS [c][t] tile; 256B-contiguous output rows.
// ---------------------------------------------------------------------------
__global__ __launch_bounds__(256) void transpose_sums_kernel(
    const float* __restrict__ qi, const float* __restrict__ qj,
    ushort* __restrict__ Qbf, float* __restrict__ p, float* __restrict__ sq)
{
    __shared__ float tile[64][132];   // [c][t] pad 132: b128-aligned rows
    const int tid = threadIdx.x;
    const int tt  = blockIdx.x;      // 0..127 (t-tile of 128)
    const int at  = blockIdx.y;      // 0..63  (a-tile of 64)
    const int t0  = tt * 128;
    const float* src = (at < 32) ? qi : qj;
    const int c0 = (at < 32 ? at : at - 32) * 64;

    // read 128 t-rows x 64 c (coalesced float4 along c), scatter to tile[c][t]
#pragma unroll
    for (int pass = 0; pass < 2; ++pass) {
        const int tl = pass * 64 + (tid >> 2);      // 0..127
        const int cl = (tid & 3) * 16;
        const float* s = src + (size_t)(t0 + tl) * CNUM + c0 + cl;
#pragma unroll
        for (int q = 0; q < 4; ++q) {
            float4 v = *(const float4*)(s + q * 4);
            tile[cl + q * 4 + 0][tl] = v.x;
            tile[cl + q * 4 + 1][tl] = v.y;
            tile[cl + q * 4 + 2][tl] = v.z;
            tile[cl + q * 4 + 3][tl] = v.w;
        }
    }
    __syncthreads();

    // write row a = at*64+al, t-chunk tseg*32..+32; vector LDS reads (b128)
    const int al   = tid >> 2;   // 0..63
    const int tseg = tid & 3;    // 0..3
    float s1 = 0.f, s2 = 0.f;
    ushort outv[32] __attribute__((aligned(16)));
#pragma unroll
    for (int k4 = 0; k4 < 8; ++k4) {
        float4 v = *(const float4*)&tile[al][tseg * 32 + k4 * 4];
        s1 += v.x + v.y + v.z + v.w;
        s2 += v.x * v.x + v.y * v.y + v.z * v.z + v.w * v.w;
        __hip_bfloat16 h0 = __float2bfloat16(v.x);
        __hip_bfloat16 h1 = __float2bfloat16(v.y);
        __hip_bfloat16 h2 = __float2bfloat16(v.z);
        __hip_bfloat16 h3 = __float2bfloat16(v.w);
        outv[k4 * 4 + 0] = *(ushort*)&h0;
        outv[k4 * 4 + 1] = *(ushort*)&h1;
        outv[k4 * 4 + 2] = *(ushort*)&h2;
        outv[k4 * 4 + 3] = *(ushort*)&h3;
    }
    const size_t dst = (size_t)(at * 64 + al) * KDIM + t0 + tseg * 32;
#pragma unroll
    for (int q = 0; q < 4; ++q)
        *(uint4*)(Qbf + dst + q * 8) = *(uint4*)&outv[q * 8];

    // combine the 4 tsegs of one column (adjacent lanes), then 1 atomic each
    s1 += __shfl_xor(s1, 1); s1 += __shfl_xor(s1, 2);
    s2 += __shfl_xor(s2, 1); s2 += __shfl_xor(s2, 2);
    if (tseg == 0) {
        atomicAdd(&p[at * 64 + al], s1);
        atomicAdd(&sq[at * 64 + al], s2);
    }
}

// ---------------------------------------------------------------------------
// Kernel 2: rnorm[a] = 1/sqrt(sumsq[a])
// ---------------------------------------------------------------------------
__global__ void rnorm_kernel(const float* __restrict__ sq, float* __restrict__ rnorm)
{
    int a = blockIdx.x * 256 + threadIdx.x;
    if (a < NROW) rnorm[a] = 1.0f / sqrtf(fmaxf(sq[a], 1e-30f));
}

// ---------------------------------------------------------------------------
// Kernel 3: 256x256-tile gram, BK=64, 8 waves, mfma_f32_16x16x32_bf16.
// Double-buffered global_load_lds staging with XOR-swizzled 16B segments:
//   LDS physical slot s of row r holds global k-segment s ^ (r&7)
//   (linear LDS dest, inverse-swizzled global source, swizzled read — rule 21).
// Epilogue: sim scaling, diag mask, pos record, per-row (max,sumexp) partials.
// Dynamic LDS: 2 bufs x 2 ops x 256 rows x 64 ushort = 128 KiB.
// ---------------------------------------------------------------------------
__global__ __launch_bounds__(512) void gram_lse_kernel(
    const ushort* __restrict__ Q, const float* __restrict__ rnorm,
    float* __restrict__ pM, float* __restrict__ pS, float* __restrict__ pos)
{
    extern __shared__ ushort L[];   // [buf][op][256][64]

    const int tid  = threadIdx.x;
    const int lane = tid & 63;
    const int wid  = tid >> 6;          // 0..7
    const int wr   = wid >> 2;          // 0..1  -> 128-row half
    const int wc   = wid & 3;           // 0..3  -> 64-col quarter
    const int g    = lane >> 4;         // k-group 0..3
    const int c15  = lane & 15;
    const int I = blockIdx.y, J = blockIdx.x;
    const int Ibase = I * BM, Jbase = J * BM;

    // Staging geometry: per round q (0..3) per operand, wave wid covers rows
    // q*64 + wid*8 .. +8, each row = 8 segments of 16B; lane l -> row offset
    // l>>3, physical slot l&7, global segment (l&7)^(l>>3) (XOR swizzle).
    const int r8 = lane >> 3;           // 0..7
    const int sseg = (lane & 7) ^ r8;   // inverse-swizzled global segment
    const ushort* gA[4];
    const ushort* gB[4];
#pragma unroll
    for (int q = 0; q < 4; ++q) {
        const int row = q * 64 + wid * 8 + r8;
        gA[q] = Q + (size_t)(Ibase + row) * KDIM + sseg * 8;
        gB[q] = Q + (size_t)(Jbase + row) * KDIM + sseg * 8;
    }

    auto stage = [&](int buf, int kt) {
        const int k0 = kt * BK;
#pragma unroll
        for (int q = 0; q < 4; ++q) {
            __builtin_amdgcn_global_load_lds(
                (const __attribute__((address_space(1))) void*)(gA[q] + k0),
                (__attribute__((address_space(3))) void*)&L[((buf * 2 + 0) * 256 + q * 64 + wid * 8) * 64],
                16, 0, 0);
            __builtin_amdgcn_global_load_lds(
                (const __attribute__((address_space(1))) void*)(gB[q] + k0),
                (__attribute__((address_space(3))) void*)&L[((buf * 2 + 1) * 256 + q * 64 + wid * 8) * 64],
                16, 0, 0);
        }
    };

    f32x4 acc[8][4] = {};

    stage(0, 0);
    __syncthreads();             // vmcnt(0) drained at barrier
    int cur = 0;
    for (int kt = 0; kt < NT; ++kt) {
        if (kt + 1 < NT) stage(cur ^ 1, kt + 1);
#pragma unroll
        for (int kh = 0; kh < 2; ++kh) {
            // swizzled read: slot = (kh*4+g) ^ (row&7), row&7 == c15&7
            const int slot = ((kh << 2) | g) ^ (c15 & 7);
            bf16x8 bfr[4], af[8];
#pragma unroll
            for (int n = 0; n < 4; ++n)
                bfr[n] = *(const bf16x8*)&L[((cur * 2 + 1) * 256 + wc * 64 + n * 16 + c15) * 64 + slot * 8];
#pragma unroll
            for (int m = 0; m < 8; ++m)
                af[m] = *(const bf16x8*)&L[((cur * 2 + 0) * 256 + wr * 128 + m * 16 + c15) * 64 + slot * 8];
#pragma unroll
            for (int m = 0; m < 8; ++m)
#pragma unroll
                for (int n = 0; n < 4; ++n)
                    acc[m][n] = __builtin_amdgcn_mfma_f32_16x16x32_bf16(af[m], bfr[n], acc[m][n], 0, 0, 0);
        }
        __syncthreads();
        cur ^= 1;
    }

    // ---- epilogue ----
    float rb[4], ra[8][4];
#pragma unroll
    for (int n = 0; n < 4; ++n) rb[n] = rnorm[Jbase + wc * 64 + n * 16 + c15];
#pragma unroll
    for (int m = 0; m < 8; ++m)
#pragma unroll
        for (int r = 0; r < 4; ++r)
            ra[m][r] = rnorm[Ibase + wr * 128 + m * 16 + g * 4 + r];

    const bool diagT = (I == J);
    const bool posT  = (J == (I ^ 8));   // partner tile (offset +-C = 8 tiles)
#pragma unroll
    for (int m = 0; m < 8; ++m) {
#pragma unroll
        for (int n = 0; n < 4; ++n) {
#pragma unroll
            for (int r = 0; r < 4; ++r) {
                float sv = acc[m][n][r] * ra[m][r] * rb[n];
                const int aoff = wr * 128 + m * 16 + g * 4 + r;
                const int boff = wc * 64 + n * 16 + c15;
                if (posT && aoff == boff) pos[Ibase + aoff] = sv;
                if (diagT && aoff == boff) sv = -1e30f;   // exclude b == a
                acc[m][n][r] = sv;
            }
        }
    }

    // per-row max and sum(exp) over this wave's 64 columns
#pragma unroll
    for (int m = 0; m < 8; ++m) {
#pragma unroll
        for (int r = 0; r < 4; ++r) {
            float mx = fmaxf(fmaxf(acc[m][0][r], acc[m][1][r]),
                             fmaxf(acc[m][2][r], acc[m][3][r]));
#pragma unroll
            for (int d = 8; d >= 1; d >>= 1) mx = fmaxf(mx, __shfl_xor(mx, d));
            float s = 0.f;
#pragma unroll
            for (int n = 0; n < 4; ++n) s += __expf(acc[m][n][r] - mx);
#pragma unroll
            for (int d = 8; d >= 1; d >>= 1) s += __shfl_xor(s, d);
            if (c15 == 0) {
                const int a  = Ibase + wr * 128 + m * 16 + g * 4 + r;
                const int Jc = J * 4 + wc;   // 64 column chunks of 64
                pM[(size_t)Jc * NROW + a] = mx;
                pS[(size_t)Jc * NROW + a] = s;
            }
        }
    }
}

// ---------------------------------------------------------------------------
// Kernel 4: combine 64 partials per row -> lse, ce = lse - pos; sum ce
// ---------------------------------------------------------------------------
__global__ __launch_bounds__(256) void combine_kernel(
    const float* __restrict__ pM, const float* __restrict__ pS,
    const float* __restrict__ pos, float* __restrict__ ce_acc)
{
    const int a = blockIdx.x * 256 + threadIdx.x;   // grid 16 -> 4096 rows
    float mx = -1e30f;
#pragma unroll 8
    for (int j = 0; j < 64; ++j) mx = fmaxf(mx, pM[(size_t)j * NROW + a]);
    float s = 0.f;
#pragma unroll 8
    for (int j = 0; j < 64; ++j)
        s += pS[(size_t)j * NROW + a] * __expf(pM[(size_t)j * NROW + a] - mx);
    float ce = mx + logf(s) - pos[a];

    float v = ce;
#pragma unroll
    for (int d = 32; d >= 1; d >>= 1) v += __shfl_xor(v, d);
    __shared__ float red[4];
    if ((threadIdx.x & 63) == 0) red[threadIdx.x >> 6] = v;
    __syncthreads();
    if (threadIdx.x == 0)
        atomicAdd(ce_acc, red[0] + red[1] + red[2] + red[3]);
}

// ---------------------------------------------------------------------------
// Kernel 5: entropy terms + final scalar
// ---------------------------------------------------------------------------
__global__ __launch_bounds__(256) void finalize_kernel(
    const float* __restrict__ p, const float* __restrict__ ce_acc,
    float* __restrict__ out)
{
    const int tid = threadIdx.x;
    float spi = 0.f, spli = 0.f, spj = 0.f, splj = 0.f;
    for (int c = tid; c < CNUM; c += 256) {
        float v = p[c];        spi += v; spli += v * logf(v);
        float w = p[CNUM + c]; spj += w; splj += w * logf(w);
    }
#pragma unroll
    for (int d = 32; d >= 1; d >>= 1) {
        spi  += __shfl_xor(spi, d);  spli += __shfl_xor(spli, d);
        spj  += __shfl_xor(spj, d);  splj += __shfl_xor(splj, d);
    }
    __shared__ float r4[4][4];
    if ((tid & 63) == 0) {
        int w = tid >> 6;
        r4[w][0] = spi; r4[w][1] = spli; r4[w][2] = spj; r4[w][3] = splj;
    }
    __syncthreads();
    if (tid == 0) {
        spi  = r4[0][0] + r4[1][0] + r4[2][0] + r4[3][0];
        spli = r4[0][1] + r4[1][1] + r4[2][1] + r4[3][1];
        spj  = r4[0][2] + r4[1][2] + r4[2][2] + r4[3][2];
        splj = r4[0][3] + r4[1][3] + r4[2][3] + r4[3][3];
        float nei = logf((float)CNUM) + spli / spi - logf(spi);
        float nej = logf((float)CNUM) + splj / spj - logf(spj);
        out[0] = ce_acc[0] / (float)NROW + nei + nej;
    }
}

// ---------------------------------------------------------------------------
extern "C" void kernel_launch(void* const* d_in, const int* in_sizes, int n_in,
                              void* d_out, int out_size, void* d_ws, size_t ws_size,
                              hipStream_t stream)
{
    const float* qi = (const float*)d_in[0];
    const float* qj = (const float*)d_in[1];
    float* out = (float*)d_out;

    char* ws = (char*)d_ws;
    const size_t QB = (size_t)NROW * KDIM * sizeof(ushort);   // 128 MiB
    ushort* Qbf  = (ushort*)ws;
    float* p     = (float*)(ws + QB);                  // 16 KiB
    float* sq    = (float*)(ws + QB + 16384);          // 16 KiB
    float* ce    = (float*)(ws + QB + 32768);          // 4 B (zeroed)
    float* rnorm = (float*)(ws + QB + 33024);          // 16 KiB
    float* pos   = (float*)(ws + QB + 49408);          // 16 KiB
    float* pM    = (float*)(ws + QB + 65792);          // 1 MiB
    float* pS    = (float*)(ws + QB + 65792 + 1048576);// 1 MiB

    // allow 128 KiB dynamic LDS for the gram kernel (host-side, idempotent)
    hipFuncSetAttribute((const void*)gram_lse_kernel,
                        hipFuncAttributeMaxDynamicSharedMemorySize, 131072);

    // zero the atomic accumulators (p, sq, ce) — ws is poisoned 0xAA each run
    hipMemsetAsync(ws + QB, 0, 33024, stream);

    dim3 gT(128, 64);
    transpose_sums_kernel<<<gT, 256, 0, stream>>>(qi, qj, Qbf, p, sq);
    rnorm_kernel<<<16, 256, 0, stream>>>(sq, rnorm);
    dim3 gG(16, 16);
    gram_lse_kernel<<<gG, 512, 131072, stream>>>(Qbf, rnorm, pM, pS, pos);
    combine_kernel<<<16, 256, 0, stream>>>(pM, pS, pos, ce);
    finalize_kernel<<<1, 256, 0, stream>>>(p, ce, out);
}